// Round 7
// baseline (132.839 us; speedup 1.0000x reference)
//
#include <hip/hip_runtime.h>
#include <hip/hip_bf16.h>

#define BATCH 4
#define SEQ   4096
#define DIN   768
#define DOUT  64

typedef __attribute__((ext_vector_type(4))) float f32x4;
typedef __attribute__((ext_vector_type(8))) short short8;
typedef __attribute__((ext_vector_type(4))) short short4v;

#define QSCALE 0.18033688011112043f  /* 0.125 * log2(e) */

static __device__ __forceinline__ unsigned short f2bf(float f) {
    union { float f; unsigned u; } un; un.f = f;
    unsigned r = un.u + 0x7FFF + ((un.u >> 16) & 1);
    return (unsigned short)(r >> 16);
}
static __device__ __forceinline__ float bf2f(unsigned short h) {
    union { unsigned u; float f; } un; un.u = ((unsigned)h) << 16;
    return un.f;
}

// ---------------------------------------------------------------------------
// Kernel 0: transpose+convert weights: wT[o][n][k] = bf16(w_o[k][n])
// ---------------------------------------------------------------------------
__global__ void wprep_kernel(const float* __restrict__ wq,
                             const float* __restrict__ wk,
                             const float* __restrict__ wv,
                             unsigned short* __restrict__ wT) {
    __shared__ float lds[64][65];
    int o = blockIdx.x / 12, kt = blockIdx.x % 12;
    const float* w = (o == 0) ? wq : (o == 1) ? wk : wv;
    int t = threadIdx.x;
    int k0 = kt * 64;
    #pragma unroll
    for (int i = 0; i < 16; ++i) {
        int flat = t + i * 256;
        int kl = flat >> 6, n = flat & 63;
        lds[kl][n] = w[(k0 + kl) * 64 + n];
    }
    __syncthreads();
    #pragma unroll
    for (int i = 0; i < 16; ++i) {
        int flat = t + i * 256;
        int n = flat >> 6, c = flat & 63;
        wT[(o * 64 + n) * 768 + k0 + c] = f2bf(lds[c][n]);
    }
}

// ---------------------------------------------------------------------------
// Kernel 1 (v3): QKV projection. 256 blocks x 256 thr, 64 rows/block,
// full-K per wave (no split-K / no combine). x staged in LDS (bf16,
// double-buffered); wT read from L2. V written TILED:
// VT[b][kv>>5][d(64)][kv&31] so attention V-tiles are contiguous 4KB.
// ---------------------------------------------------------------------------
__global__ void __launch_bounds__(256) proj_kernel(
        const float* __restrict__ x,
        const float* __restrict__ bq,
        const float* __restrict__ bk,
        const float* __restrict__ bv,
        const unsigned short* __restrict__ wT,
        unsigned short* __restrict__ Qo,
        unsigned short* __restrict__ Ko,
        unsigned short* __restrict__ VTo) {
    __shared__ unsigned short xs[2][64][40];   // 10.2 KB, row pitch 80B

    int tid = threadIdx.x;
    int wid = tid >> 6;
    int lane = tid & 63;
    int m = lane & 15, g = lane >> 4;
    int r0 = blockIdx.x * 64;

    int srow = tid >> 2, scg = tid & 3;       // staging: row, col-group of 8

    f32x4 acc[3][4];
    #pragma unroll
    for (int o = 0; o < 3; ++o)
        #pragma unroll
        for (int t = 0; t < 4; ++t)
            acc[o][t] = (f32x4){0.f, 0.f, 0.f, 0.f};

    // stage chunk 0
    {
        const float* xp = x + (size_t)(r0 + srow) * DIN + scg * 8;
        float4 lo = *(const float4*)xp;
        float4 hi = *(const float4*)(xp + 4);
        short8 v;
        v[0] = (short)f2bf(lo.x); v[1] = (short)f2bf(lo.y);
        v[2] = (short)f2bf(lo.z); v[3] = (short)f2bf(lo.w);
        v[4] = (short)f2bf(hi.x); v[5] = (short)f2bf(hi.y);
        v[6] = (short)f2bf(hi.z); v[7] = (short)f2bf(hi.w);
        *(short8*)&xs[0][srow][scg * 8] = v;
    }
    __syncthreads();

    for (int kc = 0; kc < 24; ++kc) {
        int bb = kc & 1;
        bool have = (kc + 1) < 24;
        float4 lo, hi;
        if (have) {  // issue next-chunk loads early (hide HBM under MFMA)
            const float* xp = x + (size_t)(r0 + srow) * DIN + (kc + 1) * 32 + scg * 8;
            lo = *(const float4*)xp;
            hi = *(const float4*)(xp + 4);
        }
        // compute chunk kc
        short8 af = *(const short8*)&xs[bb][wid * 16 + m][g * 8];
        int k0 = kc * 32 + g * 8;
        #pragma unroll
        for (int o = 0; o < 3; ++o) {
            #pragma unroll
            for (int t = 0; t < 4; ++t) {
                short8 bfrg = *(const short8*)(wT + (size_t)(o * 64 + t * 16 + m) * DIN + k0);
                acc[o][t] = __builtin_amdgcn_mfma_f32_16x16x32_bf16(af, bfrg, acc[o][t], 0, 0, 0);
            }
        }
        if (have) {
            short8 v;
            v[0] = (short)f2bf(lo.x); v[1] = (short)f2bf(lo.y);
            v[2] = (short)f2bf(lo.z); v[3] = (short)f2bf(lo.w);
            v[4] = (short)f2bf(hi.x); v[5] = (short)f2bf(hi.y);
            v[6] = (short)f2bf(hi.z); v[7] = (short)f2bf(hi.w);
            *(short8*)&xs[bb ^ 1][srow][scg * 8] = v;
        }
        __syncthreads();
    }

    // epilogue
    #pragma unroll
    for (int o = 0; o < 3; ++o) {
        const float* bias_p = (o == 0) ? bq : (o == 1) ? bk : bv;
        #pragma unroll
        for (int t = 0; t < 4; ++t) {
            float bias = bias_p[t * 16 + m];
            #pragma unroll
            for (int r = 0; r < 4; ++r) {
                int row = r0 + wid * 16 + g * 4 + r;
                float val = acc[o][t][r] + bias;
                if (o == 0) {
                    Qo[row * 64 + t * 16 + m] = f2bf(val * QSCALE);
                } else if (o == 1) {
                    Ko[row * 64 + t * 16 + m] = f2bf(val);
                } else {
                    int bb2 = row >> 12, ss = row & 4095;
                    // tiled: VT[b][ss>>5][d=t*16+m][ss&31]
                    VTo[(size_t)bb2 * SEQ * 64 + (size_t)(ss >> 5) * 2048
                        + (t * 16 + m) * 32 + (ss & 31)] = f2bf(val);
                }
            }
        }
    }
}

// ---------------------------------------------------------------------------
// Kernel 2 (v4): causal flash attention. 512 blocks x 512 thr.
// Each block: 32 q-rows (two 16-row tiles share K/V loads), 8-way KV split.
// V read from TILED layout (contiguous 4KB per step-tile) — fixes the
// 8KB-stride L2 set-conflict serialization diagnosed from rounds 4-6.
// Defer-max (THR=8) + free row-sum via ones-column MFMA. bf16 partial accs.
// ---------------------------------------------------------------------------
__global__ void __launch_bounds__(512, 4) attn_kernel(
        const unsigned short* __restrict__ Q,
        const unsigned short* __restrict__ K,
        const unsigned short* __restrict__ VT,
        float* __restrict__ out) {
    __shared__ __align__(16) unsigned short P_lds[8][32][36];   // 18.4 KB
    __shared__ __align__(16) unsigned short pacc[8][16][68];    // 17.4 KB (bf16)
    __shared__ float pm[8][16];
    __shared__ float pl[8][16];

    int j = blockIdx.x;
    int b = (j & 7) >> 1;                               // XCD-pinned batch
    int pair = 127 - ((j >> 3) * 2 + (j & 1));          // longest-first
    int q0 = pair * 32;
    int nsteps = pair + 1;
    int tid = threadIdx.x;
    int w = tid >> 6;
    int lane = tid & 63;
    int m = lane & 15, g = lane >> 4;

    const unsigned short* Qb = Q + (size_t)(b * SEQ + q0 + m) * DOUT + g * 8;
    short8 qf[2][2];
    qf[0][0] = *(const short8*)(Qb);
    qf[0][1] = *(const short8*)(Qb + 32);
    qf[1][0] = *(const short8*)(Qb + 16 * DOUT);
    qf[1][1] = *(const short8*)(Qb + 16 * DOUT + 32);

    short8 onesB = (short8){0,0,0,0,0,0,0,0};
    if (m == 0) {
        #pragma unroll
        for (int jj = 0; jj < 8; ++jj) onesB[jj] = (short)0x3F80;  // bf16(1.0)
    }

    f32x4 acc[2][5];
    #pragma unroll
    for (int rt = 0; rt < 2; ++rt)
        #pragma unroll
        for (int t = 0; t < 5; ++t) acc[rt][t] = (f32x4){0.f, 0.f, 0.f, 0.f};
    float mrun[2][4];
    #pragma unroll
    for (int rt = 0; rt < 2; ++rt)
        #pragma unroll
        for (int r = 0; r < 4; ++r) mrun[rt][r] = -INFINITY;

    const unsigned short* Kb = K + (size_t)(b * SEQ) * DOUT;
    const unsigned short* Vb = VT + (size_t)b * SEQ * 64;

    for (int s = w; s < nsteps; s += 8) {
        int kv0 = s * 32;
        // V tile: contiguous 4KB block [s][64 d][32 kv]
        short8 vcur[4];
        #pragma unroll
        for (int t = 0; t < 4; ++t)
            vcur[t] = *(const short8*)(Vb + (size_t)s * 2048 + (t * 16 + m) * 32 + g * 8);
        // K tile
        short8 kf[4];
        #pragma unroll
        for (int tt = 0; tt < 2; ++tt) {
            const unsigned short* kp = Kb + (size_t)(kv0 + tt * 16 + m) * DOUT + g * 8;
            kf[tt * 2 + 0] = *(const short8*)(kp);
            kf[tt * 2 + 1] = *(const short8*)(kp + 32);
        }
        bool last = (s == nsteps - 1);

        #pragma unroll
        for (int rt = 0; rt < 2; ++rt) {
            f32x4 sc[2];
            sc[0] = (f32x4){0.f, 0.f, 0.f, 0.f};
            sc[1] = (f32x4){0.f, 0.f, 0.f, 0.f};
            sc[0] = __builtin_amdgcn_mfma_f32_16x16x32_bf16(qf[rt][0], kf[0], sc[0], 0, 0, 0);
            sc[0] = __builtin_amdgcn_mfma_f32_16x16x32_bf16(qf[rt][1], kf[1], sc[0], 0, 0, 0);
            sc[1] = __builtin_amdgcn_mfma_f32_16x16x32_bf16(qf[rt][0], kf[2], sc[1], 0, 0, 0);
            sc[1] = __builtin_amdgcn_mfma_f32_16x16x32_bf16(qf[rt][1], kf[3], sc[1], 0, 0, 0);

            if (last) {
                #pragma unroll
                for (int tt = 0; tt < 2; ++tt)
                    #pragma unroll
                    for (int r = 0; r < 4; ++r)
                        if (kv0 + tt * 16 + m > q0 + rt * 16 + g * 4 + r) sc[tt][r] = -INFINITY;
            }

            // defer-max (THR = 8)
            bool need = false;
            #pragma unroll
            for (int r = 0; r < 4; ++r) {
                float th = mrun[rt][r] + 8.0f;
                need = need | (sc[0][r] > th) | (sc[1][r] > th);
            }
            if (__any(need)) {
                float rmax[4];
                #pragma unroll
                for (int r = 0; r < 4; ++r) rmax[r] = fmaxf(sc[0][r], sc[1][r]);
                #pragma unroll
                for (int msk = 1; msk <= 8; msk <<= 1)
                    #pragma unroll
                    for (int r = 0; r < 4; ++r)
                        rmax[r] = fmaxf(rmax[r], __shfl_xor(rmax[r], msk));
                #pragma unroll
                for (int r = 0; r < 4; ++r) {
                    float mnew = fmaxf(mrun[rt][r], rmax[r]);
                    float alpha = __builtin_amdgcn_exp2f(mrun[rt][r] - mnew);
                    mrun[rt][r] = mnew;
                    #pragma unroll
                    for (int t = 0; t < 5; ++t) acc[rt][t][r] *= alpha;
                }
            }

            // P -> LDS (bf16, bounded by 2^8), read back as A-frag
            #pragma unroll
            for (int tt = 0; tt < 2; ++tt)
                #pragma unroll
                for (int r = 0; r < 4; ++r)
                    P_lds[w][rt * 16 + g * 4 + r][tt * 16 + m] =
                        f2bf(__builtin_amdgcn_exp2f(sc[tt][r] - mrun[rt][r]));
            short8 pa = *(const short8*)&P_lds[w][rt * 16 + m][g * 8];

            #pragma unroll
            for (int t = 0; t < 4; ++t)
                acc[rt][t] = __builtin_amdgcn_mfma_f32_16x16x32_bf16(pa, vcur[t], acc[rt][t], 0, 0, 0);
            acc[rt][4] = __builtin_amdgcn_mfma_f32_16x16x32_bf16(pa, onesB, acc[rt][4], 0, 0, 0);
        }
    }

    // combine, one row-tile at a time (pacc reused)
    #pragma unroll
    for (int rt = 0; rt < 2; ++rt) {
        if (m == 0) {
            #pragma unroll
            for (int r = 0; r < 4; ++r) {
                pm[w][g * 4 + r] = mrun[rt][r];
                pl[w][g * 4 + r] = acc[rt][4][r];
            }
        }
        #pragma unroll
        for (int t = 0; t < 4; ++t)
            #pragma unroll
            for (int r = 0; r < 4; ++r)
                pacc[w][g * 4 + r][t * 16 + m] = f2bf(acc[rt][t][r]);
        __syncthreads();

        if (tid < 256) {
            int row = tid >> 4;
            int c4 = (tid & 15) * 4;
            float mmax = pm[0][row];
            #pragma unroll
            for (int w2 = 1; w2 < 8; ++w2) mmax = fmaxf(mmax, pm[w2][row]);
            float lt = 0.f;
            float o0 = 0.f, o1 = 0.f, o2 = 0.f, o3 = 0.f;
            #pragma unroll
            for (int w2 = 0; w2 < 8; ++w2) {
                float sc2 = __builtin_amdgcn_exp2f(pm[w2][row] - mmax);
                lt += pl[w2][row] * sc2;
                short4v pa4 = *(const short4v*)&pacc[w2][row][c4];
                o0 += bf2f((unsigned short)pa4[0]) * sc2;
                o1 += bf2f((unsigned short)pa4[1]) * sc2;
                o2 += bf2f((unsigned short)pa4[2]) * sc2;
                o3 += bf2f((unsigned short)pa4[3]) * sc2;
            }
            float invl = 1.0f / lt;
            float4 res = make_float4(o0 * invl, o1 * invl, o2 * invl, o3 * invl);
            *(float4*)&out[(size_t)(b * SEQ + q0 + rt * 16 + row) * DOUT + c4] = res;
        }
        __syncthreads();
    }
}

// ---------------------------------------------------------------------------
extern "C" void kernel_launch(void* const* d_in, const int* in_sizes, int n_in,
                              void* d_out, int out_size, void* d_ws, size_t ws_size,
                              hipStream_t stream) {
    const float* x  = (const float*)d_in[0];
    const float* wq = (const float*)d_in[1];
    const float* bq = (const float*)d_in[2];
    const float* wk = (const float*)d_in[3];
    const float* bk = (const float*)d_in[4];
    const float* wv = (const float*)d_in[5];
    const float* bv = (const float*)d_in[6];
    float* out = (float*)d_out;

    char* ws = (char*)d_ws;
    unsigned short* wT = (unsigned short*)ws;                       // 294912 B
    unsigned short* Q  = (unsigned short*)(ws + 294912);            // 2 MB
    unsigned short* K  = (unsigned short*)(ws + 294912 + 2097152);  // 2 MB
    unsigned short* VT = (unsigned short*)(ws + 294912 + 4194304);  // 2 MB (tiled)

    wprep_kernel<<<36, 256, 0, stream>>>(wq, wk, wv, wT);
    proj_kernel<<<256, 256, 0, stream>>>(x, bq, bk, bv, wT, Q, K, VT);
    attn_kernel<<<512, 512, 0, stream>>>(Q, K, VT, out);
}

// Round 8
// 127.580 us; speedup vs baseline: 1.0412x; 1.0412x over previous
//
#include <hip/hip_runtime.h>
#include <hip/hip_bf16.h>

#define BATCH 4
#define SEQ   4096
#define DIN   768
#define DOUT  64

typedef __attribute__((ext_vector_type(4))) float f32x4;
typedef __attribute__((ext_vector_type(8))) short short8;
typedef __attribute__((ext_vector_type(4))) short short4v;

#define QSCALE 0.18033688011112043f  /* 0.125 * log2(e) */

static __device__ __forceinline__ unsigned short f2bf(float f) {
    union { float f; unsigned u; } un; un.f = f;
    unsigned r = un.u + 0x7FFF + ((un.u >> 16) & 1);
    return (unsigned short)(r >> 16);
}
static __device__ __forceinline__ float bf2f(unsigned short h) {
    union { unsigned u; float f; } un; un.u = ((unsigned)h) << 16;
    return un.f;
}

// ---------------------------------------------------------------------------
// Kernel 0: transpose+convert weights: wT[o][n][k] = bf16(w_o[k][n])
// ---------------------------------------------------------------------------
__global__ void wprep_kernel(const float* __restrict__ wq,
                             const float* __restrict__ wk,
                             const float* __restrict__ wv,
                             unsigned short* __restrict__ wT) {
    __shared__ float lds[64][65];
    int o = blockIdx.x / 12, kt = blockIdx.x % 12;
    const float* w = (o == 0) ? wq : (o == 1) ? wk : wv;
    int t = threadIdx.x;
    int k0 = kt * 64;
    #pragma unroll
    for (int i = 0; i < 16; ++i) {
        int flat = t + i * 256;
        int kl = flat >> 6, n = flat & 63;
        lds[kl][n] = w[(k0 + kl) * 64 + n];
    }
    __syncthreads();
    #pragma unroll
    for (int i = 0; i < 16; ++i) {
        int flat = t + i * 256;
        int n = flat >> 6, c = flat & 63;
        wT[(o * 64 + n) * 768 + k0 + c] = f2bf(lds[c][n]);
    }
}

// ---------------------------------------------------------------------------
// Kernel 1 (v5): QKV projection. 1024 blocks x 64 thr = 1024 independent
// waves (16 rows each), NO LDS, NO barriers. x prefetched 2 chunks deep in
// registers (HBM latency hidden); wT streamed from L2 in-loop.
// __launch_bounds__(64,4): VGPR<=128 so 4 waves/SIMD co-reside.
// V written TILED: VT[b][kv>>5][d(64)][kv&31] (contiguous 4KB attn tiles).
// ---------------------------------------------------------------------------
__global__ void __launch_bounds__(64, 4) proj_kernel(
        const float* __restrict__ x,
        const float* __restrict__ bq,
        const float* __restrict__ bk,
        const float* __restrict__ bv,
        const unsigned short* __restrict__ wT,
        unsigned short* __restrict__ Qo,
        unsigned short* __restrict__ Ko,
        unsigned short* __restrict__ VTo) {
    int lane = threadIdx.x;
    int m = lane & 15, g = lane >> 4;
    int r0 = blockIdx.x * 16;

    const float* xrow = x + (size_t)(r0 + m) * DIN + g * 8;

    f32x4 acc[3][4];
    #pragma unroll
    for (int o = 0; o < 3; ++o)
        #pragma unroll
        for (int t = 0; t < 4; ++t)
            acc[o][t] = (f32x4){0.f, 0.f, 0.f, 0.f};

    // 2-deep x prefetch
    float4 xa[2], xb[2];
    xa[0] = *(const float4*)(xrow);
    xb[0] = *(const float4*)(xrow + 4);
    xa[1] = *(const float4*)(xrow + 32);
    xb[1] = *(const float4*)(xrow + 36);

    #pragma unroll
    for (int kc = 0; kc < 24; ++kc) {
        int cur = kc & 1;
        // convert current chunk to bf16 A-frag
        short8 af;
        af[0] = (short)f2bf(xa[cur].x); af[1] = (short)f2bf(xa[cur].y);
        af[2] = (short)f2bf(xa[cur].z); af[3] = (short)f2bf(xa[cur].w);
        af[4] = (short)f2bf(xb[cur].x); af[5] = (short)f2bf(xb[cur].y);
        af[6] = (short)f2bf(xb[cur].z); af[7] = (short)f2bf(xb[cur].w);
        // refill this buffer with chunk kc+2 (af already holds the data)
        if (kc + 2 < 24) {
            xa[cur] = *(const float4*)(xrow + (kc + 2) * 32);
            xb[cur] = *(const float4*)(xrow + (kc + 2) * 32 + 4);
        }
        int k0 = kc * 32 + g * 8;
        #pragma unroll
        for (int o = 0; o < 3; ++o) {
            #pragma unroll
            for (int t = 0; t < 4; ++t) {
                short8 bfrg = *(const short8*)(wT + (size_t)(o * 64 + t * 16 + m) * DIN + k0);
                acc[o][t] = __builtin_amdgcn_mfma_f32_16x16x32_bf16(af, bfrg, acc[o][t], 0, 0, 0);
            }
        }
    }

    // epilogue
    #pragma unroll
    for (int o = 0; o < 3; ++o) {
        const float* bias_p = (o == 0) ? bq : (o == 1) ? bk : bv;
        #pragma unroll
        for (int t = 0; t < 4; ++t) {
            float bias = bias_p[t * 16 + m];
            #pragma unroll
            for (int r = 0; r < 4; ++r) {
                int row = r0 + g * 4 + r;
                float val = acc[o][t][r] + bias;
                if (o == 0) {
                    Qo[row * 64 + t * 16 + m] = f2bf(val * QSCALE);
                } else if (o == 1) {
                    Ko[row * 64 + t * 16 + m] = f2bf(val);
                } else {
                    int bb2 = row >> 12, ss = row & 4095;
                    VTo[(size_t)bb2 * SEQ * 64 + (size_t)(ss >> 5) * 2048
                        + (t * 16 + m) * 32 + (ss & 31)] = f2bf(val);
                }
            }
        }
    }
}

// ---------------------------------------------------------------------------
// Kernel 2 (v4, unchanged): causal flash attention. 512 blocks x 512 thr.
// 32 q-rows/block (two 16-row tiles share K/V loads), 8-way KV split,
// tiled V, defer-max (THR=8), free row-sum via ones-column MFMA.
// ---------------------------------------------------------------------------
__global__ void __launch_bounds__(512, 4) attn_kernel(
        const unsigned short* __restrict__ Q,
        const unsigned short* __restrict__ K,
        const unsigned short* __restrict__ VT,
        float* __restrict__ out) {
    __shared__ __align__(16) unsigned short P_lds[8][32][36];
    __shared__ __align__(16) unsigned short pacc[8][16][68];
    __shared__ float pm[8][16];
    __shared__ float pl[8][16];

    int j = blockIdx.x;
    int b = (j & 7) >> 1;
    int pair = 127 - ((j >> 3) * 2 + (j & 1));
    int q0 = pair * 32;
    int nsteps = pair + 1;
    int tid = threadIdx.x;
    int w = tid >> 6;
    int lane = tid & 63;
    int m = lane & 15, g = lane >> 4;

    const unsigned short* Qb = Q + (size_t)(b * SEQ + q0 + m) * DOUT + g * 8;
    short8 qf[2][2];
    qf[0][0] = *(const short8*)(Qb);
    qf[0][1] = *(const short8*)(Qb + 32);
    qf[1][0] = *(const short8*)(Qb + 16 * DOUT);
    qf[1][1] = *(const short8*)(Qb + 16 * DOUT + 32);

    short8 onesB = (short8){0,0,0,0,0,0,0,0};
    if (m == 0) {
        #pragma unroll
        for (int jj = 0; jj < 8; ++jj) onesB[jj] = (short)0x3F80;
    }

    f32x4 acc[2][5];
    #pragma unroll
    for (int rt = 0; rt < 2; ++rt)
        #pragma unroll
        for (int t = 0; t < 5; ++t) acc[rt][t] = (f32x4){0.f, 0.f, 0.f, 0.f};
    float mrun[2][4];
    #pragma unroll
    for (int rt = 0; rt < 2; ++rt)
        #pragma unroll
        for (int r = 0; r < 4; ++r) mrun[rt][r] = -INFINITY;

    const unsigned short* Kb = K + (size_t)(b * SEQ) * DOUT;
    const unsigned short* Vb = VT + (size_t)b * SEQ * 64;

    for (int s = w; s < nsteps; s += 8) {
        int kv0 = s * 32;
        short8 vcur[4];
        #pragma unroll
        for (int t = 0; t < 4; ++t)
            vcur[t] = *(const short8*)(Vb + (size_t)s * 2048 + (t * 16 + m) * 32 + g * 8);
        short8 kf[4];
        #pragma unroll
        for (int tt = 0; tt < 2; ++tt) {
            const unsigned short* kp = Kb + (size_t)(kv0 + tt * 16 + m) * DOUT + g * 8;
            kf[tt * 2 + 0] = *(const short8*)(kp);
            kf[tt * 2 + 1] = *(const short8*)(kp + 32);
        }
        bool last = (s == nsteps - 1);

        #pragma unroll
        for (int rt = 0; rt < 2; ++rt) {
            f32x4 sc[2];
            sc[0] = (f32x4){0.f, 0.f, 0.f, 0.f};
            sc[1] = (f32x4){0.f, 0.f, 0.f, 0.f};
            sc[0] = __builtin_amdgcn_mfma_f32_16x16x32_bf16(qf[rt][0], kf[0], sc[0], 0, 0, 0);
            sc[0] = __builtin_amdgcn_mfma_f32_16x16x32_bf16(qf[rt][1], kf[1], sc[0], 0, 0, 0);
            sc[1] = __builtin_amdgcn_mfma_f32_16x16x32_bf16(qf[rt][0], kf[2], sc[1], 0, 0, 0);
            sc[1] = __builtin_amdgcn_mfma_f32_16x16x32_bf16(qf[rt][1], kf[3], sc[1], 0, 0, 0);

            if (last) {
                #pragma unroll
                for (int tt = 0; tt < 2; ++tt)
                    #pragma unroll
                    for (int r = 0; r < 4; ++r)
                        if (kv0 + tt * 16 + m > q0 + rt * 16 + g * 4 + r) sc[tt][r] = -INFINITY;
            }

            bool need = false;
            #pragma unroll
            for (int r = 0; r < 4; ++r) {
                float th = mrun[rt][r] + 8.0f;
                need = need | (sc[0][r] > th) | (sc[1][r] > th);
            }
            if (__any(need)) {
                float rmax[4];
                #pragma unroll
                for (int r = 0; r < 4; ++r) rmax[r] = fmaxf(sc[0][r], sc[1][r]);
                #pragma unroll
                for (int msk = 1; msk <= 8; msk <<= 1)
                    #pragma unroll
                    for (int r = 0; r < 4; ++r)
                        rmax[r] = fmaxf(rmax[r], __shfl_xor(rmax[r], msk));
                #pragma unroll
                for (int r = 0; r < 4; ++r) {
                    float mnew = fmaxf(mrun[rt][r], rmax[r]);
                    float alpha = __builtin_amdgcn_exp2f(mrun[rt][r] - mnew);
                    mrun[rt][r] = mnew;
                    #pragma unroll
                    for (int t = 0; t < 5; ++t) acc[rt][t][r] *= alpha;
                }
            }

            #pragma unroll
            for (int tt = 0; tt < 2; ++tt)
                #pragma unroll
                for (int r = 0; r < 4; ++r)
                    P_lds[w][rt * 16 + g * 4 + r][tt * 16 + m] =
                        f2bf(__builtin_amdgcn_exp2f(sc[tt][r] - mrun[rt][r]));
            short8 pa = *(const short8*)&P_lds[w][rt * 16 + m][g * 8];

            #pragma unroll
            for (int t = 0; t < 4; ++t)
                acc[rt][t] = __builtin_amdgcn_mfma_f32_16x16x32_bf16(pa, vcur[t], acc[rt][t], 0, 0, 0);
            acc[rt][4] = __builtin_amdgcn_mfma_f32_16x16x32_bf16(pa, onesB, acc[rt][4], 0, 0, 0);
        }
    }

    #pragma unroll
    for (int rt = 0; rt < 2; ++rt) {
        if (m == 0) {
            #pragma unroll
            for (int r = 0; r < 4; ++r) {
                pm[w][g * 4 + r] = mrun[rt][r];
                pl[w][g * 4 + r] = acc[rt][4][r];
            }
        }
        #pragma unroll
        for (int t = 0; t < 4; ++t)
            #pragma unroll
            for (int r = 0; r < 4; ++r)
                pacc[w][g * 4 + r][t * 16 + m] = f2bf(acc[rt][t][r]);
        __syncthreads();

        if (tid < 256) {
            int row = tid >> 4;
            int c4 = (tid & 15) * 4;
            float mmax = pm[0][row];
            #pragma unroll
            for (int w2 = 1; w2 < 8; ++w2) mmax = fmaxf(mmax, pm[w2][row]);
            float lt = 0.f;
            float o0 = 0.f, o1 = 0.f, o2 = 0.f, o3 = 0.f;
            #pragma unroll
            for (int w2 = 0; w2 < 8; ++w2) {
                float sc2 = __builtin_amdgcn_exp2f(pm[w2][row] - mmax);
                lt += pl[w2][row] * sc2;
                short4v pa4 = *(const short4v*)&pacc[w2][row][c4];
                o0 += bf2f((unsigned short)pa4[0]) * sc2;
                o1 += bf2f((unsigned short)pa4[1]) * sc2;
                o2 += bf2f((unsigned short)pa4[2]) * sc2;
                o3 += bf2f((unsigned short)pa4[3]) * sc2;
            }
            float invl = 1.0f / lt;
            float4 res = make_float4(o0 * invl, o1 * invl, o2 * invl, o3 * invl);
            *(float4*)&out[(size_t)(b * SEQ + q0 + rt * 16 + row) * DOUT + c4] = res;
        }
        __syncthreads();
    }
}

// ---------------------------------------------------------------------------
extern "C" void kernel_launch(void* const* d_in, const int* in_sizes, int n_in,
                              void* d_out, int out_size, void* d_ws, size_t ws_size,
                              hipStream_t stream) {
    const float* x  = (const float*)d_in[0];
    const float* wq = (const float*)d_in[1];
    const float* bq = (const float*)d_in[2];
    const float* wk = (const float*)d_in[3];
    const float* bk = (const float*)d_in[4];
    const float* wv = (const float*)d_in[5];
    const float* bv = (const float*)d_in[6];
    float* out = (float*)d_out;

    char* ws = (char*)d_ws;
    unsigned short* wT = (unsigned short*)ws;                       // 294912 B
    unsigned short* Q  = (unsigned short*)(ws + 294912);            // 2 MB
    unsigned short* K  = (unsigned short*)(ws + 294912 + 2097152);  // 2 MB
    unsigned short* VT = (unsigned short*)(ws + 294912 + 4194304);  // 2 MB (tiled)

    wprep_kernel<<<36, 256, 0, stream>>>(wq, wk, wv, wT);
    proj_kernel<<<1024, 64, 0, stream>>>(x, bq, bk, bv, wT, Q, K, VT);
    attn_kernel<<<512, 512, 0, stream>>>(Q, K, VT, out);
}

// Round 9
// 94.850 us; speedup vs baseline: 1.4005x; 1.3451x over previous
//
#include <hip/hip_runtime.h>
#include <hip/hip_bf16.h>

#define BATCH 4
#define SEQ   4096
#define DIN   768
#define DOUT  64

typedef __attribute__((ext_vector_type(4))) float f32x4;
typedef __attribute__((ext_vector_type(8))) short short8;
typedef __attribute__((ext_vector_type(4))) short short4v;

#define QSCALE 0.18033688011112043f  /* 0.125 * log2(e) */

static __device__ __forceinline__ unsigned short f2bf(float f) {
    union { float f; unsigned u; } un; un.f = f;
    unsigned r = un.u + 0x7FFF + ((un.u >> 16) & 1);
    return (unsigned short)(r >> 16);
}
static __device__ __forceinline__ float bf2f(unsigned short h) {
    union { unsigned u; float f; } un; un.u = ((unsigned)h) << 16;
    return un.f;
}

// ---------------------------------------------------------------------------
// Kernel 0: transpose+convert weights: wT[o][n][k] = bf16(w_o[k][n])
// ---------------------------------------------------------------------------
__global__ void wprep_kernel(const float* __restrict__ wq,
                             const float* __restrict__ wk,
                             const float* __restrict__ wv,
                             unsigned short* __restrict__ wT) {
    __shared__ float lds[64][65];
    int o = blockIdx.x / 12, kt = blockIdx.x % 12;
    const float* w = (o == 0) ? wq : (o == 1) ? wk : wv;
    int t = threadIdx.x;
    int k0 = kt * 64;
    #pragma unroll
    for (int i = 0; i < 16; ++i) {
        int flat = t + i * 256;
        int kl = flat >> 6, n = flat & 63;
        lds[kl][n] = w[(k0 + kl) * 64 + n];
    }
    __syncthreads();
    #pragma unroll
    for (int i = 0; i < 16; ++i) {
        int flat = t + i * 256;
        int n = flat >> 6, c = flat & 63;
        wT[(o * 64 + n) * 768 + k0 + c] = f2bf(lds[c][n]);
    }
}

// ---------------------------------------------------------------------------
// Kernel 1 (v6): QKV projection.
// 1024 blocks x 256 thr (4 waves) -> 4 blocks/CU, 4 waves/SIMD (real TLP).
// Block owns 16 rows: x staged ONCE to LDS (bf16, padded pitch), 1 barrier.
// Waves split the 12 column-tiles (3 each) -> 3 B-frags + 3 MFMAs per chunk
// (fits registers; loads pipeline; no split-K combine; x HBM traffic 1x).
// V written TILED: VT[b][kv>>5][d(64)][kv&31].
// ---------------------------------------------------------------------------
__global__ void __launch_bounds__(256) proj_kernel(
        const float* __restrict__ x,
        const float* __restrict__ bq,
        const float* __restrict__ bk,
        const float* __restrict__ bv,
        const unsigned short* __restrict__ wT,
        unsigned short* __restrict__ Qo,
        unsigned short* __restrict__ Ko,
        unsigned short* __restrict__ VTo) {
    __shared__ __align__(16) unsigned short xs[16][776];   // 24.8 KB

    int tid = threadIdx.x;
    int w = tid >> 6;
    int lane = tid & 63;
    int m = lane & 15, g = lane >> 4;
    int r0 = blockIdx.x * 16;

    // stage x[r0:r0+16][0:768] -> bf16 LDS; fully coalesced float4 loads
    {
        const float* xbase = x + (size_t)r0 * DIN;
        #pragma unroll
        for (int i = 0; i < 12; ++i) {
            int flat4 = tid + i * 256;            // float4 index, 0..3071
            int row = flat4 / 192;                // 192 float4 per row
            int c4 = flat4 - row * 192;
            float4 v = *(const float4*)(xbase + (size_t)row * DIN + c4 * 4);
            short4v sv;
            sv[0] = (short)f2bf(v.x); sv[1] = (short)f2bf(v.y);
            sv[2] = (short)f2bf(v.z); sv[3] = (short)f2bf(v.w);
            *(short4v*)&xs[row][c4 * 4] = sv;
        }
    }
    __syncthreads();

    // wave w computes column-tiles nc = 3w .. 3w+2 (48 of 192 cols)
    f32x4 acc[3];
    #pragma unroll
    for (int t = 0; t < 3; ++t) acc[t] = (f32x4){0.f, 0.f, 0.f, 0.f};

    for (int kc = 0; kc < 24; ++kc) {
        short8 af = *(const short8*)&xs[m][kc * 32 + g * 8];
        #pragma unroll
        for (int tt = 0; tt < 3; ++tt) {
            int n = (w * 3 + tt) * 16 + m;        // global col 0..191
            short8 bfrg = *(const short8*)(wT + (size_t)n * DIN + kc * 32 + g * 8);
            acc[tt] = __builtin_amdgcn_mfma_f32_16x16x32_bf16(af, bfrg, acc[tt], 0, 0, 0);
        }
    }

    // epilogue: wave w writes its 3 column-tiles
    #pragma unroll
    for (int tt = 0; tt < 3; ++tt) {
        int nc = w * 3 + tt;      // 0..11
        int o = nc >> 2;          // 0=Q 1=K 2=V
        int t = nc & 3;           // 16-col tile within o
        const float* bias_p = (o == 0) ? bq : (o == 1) ? bk : bv;
        float bias = bias_p[t * 16 + m];
        #pragma unroll
        for (int r = 0; r < 4; ++r) {
            int row = r0 + g * 4 + r;
            float val = acc[tt][r] + bias;
            if (o == 0) {
                Qo[row * 64 + t * 16 + m] = f2bf(val * QSCALE);
            } else if (o == 1) {
                Ko[row * 64 + t * 16 + m] = f2bf(val);
            } else {
                int bb2 = row >> 12, ss = row & 4095;
                VTo[(size_t)bb2 * SEQ * 64 + (size_t)(ss >> 5) * 2048
                    + (t * 16 + m) * 32 + (ss & 31)] = f2bf(val);
            }
        }
    }
}

// ---------------------------------------------------------------------------
// Kernel 2 (v4, unchanged): causal flash attention. 512 blocks x 512 thr.
// 32 q-rows/block (two 16-row tiles share K/V loads), 8-way KV split,
// tiled V, defer-max (THR=8), free row-sum via ones-column MFMA.
// ---------------------------------------------------------------------------
__global__ void __launch_bounds__(512, 4) attn_kernel(
        const unsigned short* __restrict__ Q,
        const unsigned short* __restrict__ K,
        const unsigned short* __restrict__ VT,
        float* __restrict__ out) {
    __shared__ __align__(16) unsigned short P_lds[8][32][36];
    __shared__ __align__(16) unsigned short pacc[8][16][68];
    __shared__ float pm[8][16];
    __shared__ float pl[8][16];

    int j = blockIdx.x;
    int b = (j & 7) >> 1;
    int pair = 127 - ((j >> 3) * 2 + (j & 1));
    int q0 = pair * 32;
    int nsteps = pair + 1;
    int tid = threadIdx.x;
    int w = tid >> 6;
    int lane = tid & 63;
    int m = lane & 15, g = lane >> 4;

    const unsigned short* Qb = Q + (size_t)(b * SEQ + q0 + m) * DOUT + g * 8;
    short8 qf[2][2];
    qf[0][0] = *(const short8*)(Qb);
    qf[0][1] = *(const short8*)(Qb + 32);
    qf[1][0] = *(const short8*)(Qb + 16 * DOUT);
    qf[1][1] = *(const short8*)(Qb + 16 * DOUT + 32);

    short8 onesB = (short8){0,0,0,0,0,0,0,0};
    if (m == 0) {
        #pragma unroll
        for (int jj = 0; jj < 8; ++jj) onesB[jj] = (short)0x3F80;
    }

    f32x4 acc[2][5];
    #pragma unroll
    for (int rt = 0; rt < 2; ++rt)
        #pragma unroll
        for (int t = 0; t < 5; ++t) acc[rt][t] = (f32x4){0.f, 0.f, 0.f, 0.f};
    float mrun[2][4];
    #pragma unroll
    for (int rt = 0; rt < 2; ++rt)
        #pragma unroll
        for (int r = 0; r < 4; ++r) mrun[rt][r] = -INFINITY;

    const unsigned short* Kb = K + (size_t)(b * SEQ) * DOUT;
    const unsigned short* Vb = VT + (size_t)b * SEQ * 64;

    for (int s = w; s < nsteps; s += 8) {
        int kv0 = s * 32;
        short8 vcur[4];
        #pragma unroll
        for (int t = 0; t < 4; ++t)
            vcur[t] = *(const short8*)(Vb + (size_t)s * 2048 + (t * 16 + m) * 32 + g * 8);
        short8 kf[4];
        #pragma unroll
        for (int tt = 0; tt < 2; ++tt) {
            const unsigned short* kp = Kb + (size_t)(kv0 + tt * 16 + m) * DOUT + g * 8;
            kf[tt * 2 + 0] = *(const short8*)(kp);
            kf[tt * 2 + 1] = *(const short8*)(kp + 32);
        }
        bool last = (s == nsteps - 1);

        #pragma unroll
        for (int rt = 0; rt < 2; ++rt) {
            f32x4 sc[2];
            sc[0] = (f32x4){0.f, 0.f, 0.f, 0.f};
            sc[1] = (f32x4){0.f, 0.f, 0.f, 0.f};
            sc[0] = __builtin_amdgcn_mfma_f32_16x16x32_bf16(qf[rt][0], kf[0], sc[0], 0, 0, 0);
            sc[0] = __builtin_amdgcn_mfma_f32_16x16x32_bf16(qf[rt][1], kf[1], sc[0], 0, 0, 0);
            sc[1] = __builtin_amdgcn_mfma_f32_16x16x32_bf16(qf[rt][0], kf[2], sc[1], 0, 0, 0);
            sc[1] = __builtin_amdgcn_mfma_f32_16x16x32_bf16(qf[rt][1], kf[3], sc[1], 0, 0, 0);

            if (last) {
                #pragma unroll
                for (int tt = 0; tt < 2; ++tt)
                    #pragma unroll
                    for (int r = 0; r < 4; ++r)
                        if (kv0 + tt * 16 + m > q0 + rt * 16 + g * 4 + r) sc[tt][r] = -INFINITY;
            }

            bool need = false;
            #pragma unroll
            for (int r = 0; r < 4; ++r) {
                float th = mrun[rt][r] + 8.0f;
                need = need | (sc[0][r] > th) | (sc[1][r] > th);
            }
            if (__any(need)) {
                float rmax[4];
                #pragma unroll
                for (int r = 0; r < 4; ++r) rmax[r] = fmaxf(sc[0][r], sc[1][r]);
                #pragma unroll
                for (int msk = 1; msk <= 8; msk <<= 1)
                    #pragma unroll
                    for (int r = 0; r < 4; ++r)
                        rmax[r] = fmaxf(rmax[r], __shfl_xor(rmax[r], msk));
                #pragma unroll
                for (int r = 0; r < 4; ++r) {
                    float mnew = fmaxf(mrun[rt][r], rmax[r]);
                    float alpha = __builtin_amdgcn_exp2f(mrun[rt][r] - mnew);
                    mrun[rt][r] = mnew;
                    #pragma unroll
                    for (int t = 0; t < 5; ++t) acc[rt][t][r] *= alpha;
                }
            }

            #pragma unroll
            for (int tt = 0; tt < 2; ++tt)
                #pragma unroll
                for (int r = 0; r < 4; ++r)
                    P_lds[w][rt * 16 + g * 4 + r][tt * 16 + m] =
                        f2bf(__builtin_amdgcn_exp2f(sc[tt][r] - mrun[rt][r]));
            short8 pa = *(const short8*)&P_lds[w][rt * 16 + m][g * 8];

            #pragma unroll
            for (int t = 0; t < 4; ++t)
                acc[rt][t] = __builtin_amdgcn_mfma_f32_16x16x32_bf16(pa, vcur[t], acc[rt][t], 0, 0, 0);
            acc[rt][4] = __builtin_amdgcn_mfma_f32_16x16x32_bf16(pa, onesB, acc[rt][4], 0, 0, 0);
        }
    }

    #pragma unroll
    for (int rt = 0; rt < 2; ++rt) {
        if (m == 0) {
            #pragma unroll
            for (int r = 0; r < 4; ++r) {
                pm[w][g * 4 + r] = mrun[rt][r];
                pl[w][g * 4 + r] = acc[rt][4][r];
            }
        }
        #pragma unroll
        for (int t = 0; t < 4; ++t)
            #pragma unroll
            for (int r = 0; r < 4; ++r)
                pacc[w][g * 4 + r][t * 16 + m] = f2bf(acc[rt][t][r]);
        __syncthreads();

        if (tid < 256) {
            int row = tid >> 4;
            int c4 = (tid & 15) * 4;
            float mmax = pm[0][row];
            #pragma unroll
            for (int w2 = 1; w2 < 8; ++w2) mmax = fmaxf(mmax, pm[w2][row]);
            float lt = 0.f;
            float o0 = 0.f, o1 = 0.f, o2 = 0.f, o3 = 0.f;
            #pragma unroll
            for (int w2 = 0; w2 < 8; ++w2) {
                float sc2 = __builtin_amdgcn_exp2f(pm[w2][row] - mmax);
                lt += pl[w2][row] * sc2;
                short4v pa4 = *(const short4v*)&pacc[w2][row][c4];
                o0 += bf2f((unsigned short)pa4[0]) * sc2;
                o1 += bf2f((unsigned short)pa4[1]) * sc2;
                o2 += bf2f((unsigned short)pa4[2]) * sc2;
                o3 += bf2f((unsigned short)pa4[3]) * sc2;
            }
            float invl = 1.0f / lt;
            float4 res = make_float4(o0 * invl, o1 * invl, o2 * invl, o3 * invl);
            *(float4*)&out[(size_t)(b * SEQ + q0 + rt * 16 + row) * DOUT + c4] = res;
        }
        __syncthreads();
    }
}

// ---------------------------------------------------------------------------
extern "C" void kernel_launch(void* const* d_in, const int* in_sizes, int n_in,
                              void* d_out, int out_size, void* d_ws, size_t ws_size,
                              hipStream_t stream) {
    const float* x  = (const float*)d_in[0];
    const float* wq = (const float*)d_in[1];
    const float* bq = (const float*)d_in[2];
    const float* wk = (const float*)d_in[3];
    const float* bk = (const float*)d_in[4];
    const float* wv = (const float*)d_in[5];
    const float* bv = (const float*)d_in[6];
    float* out = (float*)d_out;

    char* ws = (char*)d_ws;
    unsigned short* wT = (unsigned short*)ws;                       // 294912 B
    unsigned short* Q  = (unsigned short*)(ws + 294912);            // 2 MB
    unsigned short* K  = (unsigned short*)(ws + 294912 + 2097152);  // 2 MB
    unsigned short* VT = (unsigned short*)(ws + 294912 + 4194304);  // 2 MB (tiled)

    wprep_kernel<<<36, 256, 0, stream>>>(wq, wk, wv, wT);
    proj_kernel<<<1024, 256, 0, stream>>>(x, bq, bk, bv, wT, Q, K, VT);
    attn_kernel<<<512, 512, 0, stream>>>(Q, K, VT, out);
}

// Round 10
// 53.992 us; speedup vs baseline: 2.4603x; 1.7567x over previous
//
#include <hip/hip_runtime.h>
#include <hip/hip_bf16.h>

#define BATCH 4
#define SEQ   4096
#define DIN   768
#define DOUT  64

typedef __attribute__((ext_vector_type(4))) float f32x4;
typedef __attribute__((ext_vector_type(8))) short short8;
typedef __attribute__((ext_vector_type(4))) short short4v;

#define QSCALE 0.18033688011112043f  /* 0.125 * log2(e) */

static __device__ __forceinline__ unsigned short f2bf(float f) {
    union { float f; unsigned u; } un; un.f = f;
    unsigned r = un.u + 0x7FFF + ((un.u >> 16) & 1);
    return (unsigned short)(r >> 16);
}
static __device__ __forceinline__ float bf2f(unsigned short h) {
    union { unsigned u; float f; } un; un.u = ((unsigned)h) << 16;
    return un.f;
}

// ---------------------------------------------------------------------------
// Kernel 0 (v2): weights -> B-fragment order.
// wF[(nc*24+kc)*512 + lane*8 + j] = w_o[kc*32 + g*8 + j][t*16 + m]
// where nc = o*4+t, lane = g*16+m. Each fragment = contiguous 1KB.
// grid = 36 blocks (3 o x 12 kt), 256 thr.
// ---------------------------------------------------------------------------
__global__ void wprep_kernel(const float* __restrict__ wq,
                             const float* __restrict__ wk,
                             const float* __restrict__ wv,
                             unsigned short* __restrict__ wF) {
    __shared__ float lds[64][65];
    int o = blockIdx.x / 12, kt = blockIdx.x % 12;
    const float* w = (o == 0) ? wq : (o == 1) ? wk : wv;
    int tid = threadIdx.x;
    int k0 = kt * 64;
    #pragma unroll
    for (int i = 0; i < 16; ++i) {
        int flat = tid + i * 256;
        int kl = flat >> 6, n = flat & 63;
        lds[kl][n] = w[(k0 + kl) * 64 + n];
    }
    __syncthreads();
    int lane = tid & 63;
    int m = lane & 15, g = lane >> 4;
    #pragma unroll
    for (int i = 0; i < 2; ++i) {
        int f = i * 4 + (tid >> 6);          // 0..7: (t, kcl)
        int t = f >> 1, kcl = f & 1;
        int kc = kt * 2 + kcl;
        int nc = o * 4 + t;
        short8 v;
        #pragma unroll
        for (int j = 0; j < 8; ++j)
            v[j] = (short)f2bf(lds[kcl * 32 + g * 8 + j][t * 16 + m]);
        *(short8*)&wF[(size_t)(nc * 24 + kc) * 512 + lane * 8] = v;
    }
}

// ---------------------------------------------------------------------------
// Kernel 1 (v7): QKV projection, fragment-order I/O.
// 1024 blocks x 256 thr (4 waves), 16 rows/block; x staged once to LDS;
// waves split 12 col-tiles (3 each). wF loads contiguous 1KB/wave.
// Epilogue: per-wave LDS transpose -> Qf/Kf/Vf in fragment order
// (contiguous 16B/lane stores).
// ---------------------------------------------------------------------------
__global__ void __launch_bounds__(256) proj_kernel(
        const float* __restrict__ x,
        const float* __restrict__ bq,
        const float* __restrict__ bk,
        const float* __restrict__ bv,
        const unsigned short* __restrict__ wF,
        unsigned short* __restrict__ Qf,
        unsigned short* __restrict__ Kf,
        unsigned short* __restrict__ Vf) {
    __shared__ __align__(16) unsigned short xs[16][776];   // 24.2 KB
    __shared__ unsigned short tr[4][16][24];               // 3 KB transpose scratch

    int tid = threadIdx.x;
    int w = tid >> 6;
    int lane = tid & 63;
    int m = lane & 15, g = lane >> 4;
    int r0 = blockIdx.x * 16;

    // stage x[r0:r0+16][0:768] -> bf16 LDS (coalesced float4)
    {
        const float* xbase = x + (size_t)r0 * DIN;
        #pragma unroll
        for (int i = 0; i < 12; ++i) {
            int flat4 = tid + i * 256;
            int row = flat4 / 192;
            int c4 = flat4 - row * 192;
            float4 v = *(const float4*)(xbase + (size_t)row * DIN + c4 * 4);
            short4v sv;
            sv[0] = (short)f2bf(v.x); sv[1] = (short)f2bf(v.y);
            sv[2] = (short)f2bf(v.z); sv[3] = (short)f2bf(v.w);
            *(short4v*)&xs[row][c4 * 4] = sv;
        }
    }
    __syncthreads();

    f32x4 acc[3];
    #pragma unroll
    for (int t = 0; t < 3; ++t) acc[t] = (f32x4){0.f, 0.f, 0.f, 0.f};

    for (int kc = 0; kc < 24; ++kc) {
        short8 af = *(const short8*)&xs[m][kc * 32 + g * 8];
        #pragma unroll
        for (int tt = 0; tt < 3; ++tt) {
            int nc = w * 3 + tt;
            short8 bfrg = *(const short8*)(wF + (size_t)(nc * 24 + kc) * 512 + lane * 8);
            acc[tt] = __builtin_amdgcn_mfma_f32_16x16x32_bf16(af, bfrg, acc[tt], 0, 0, 0);
        }
    }

    // epilogue: bias, LDS transpose, fragment-order stores
    int b2 = r0 >> 12;
    int ss = r0 & 4095;
    int s = ss >> 5, half = (ss >> 4) & 1;
    #pragma unroll
    for (int tt = 0; tt < 3; ++tt) {
        int nc = w * 3 + tt;
        int o = nc >> 2;
        int t = nc & 3;
        const float* bias_p = (o == 0) ? bq : (o == 1) ? bk : bv;
        float bias = bias_p[t * 16 + m];
        #pragma unroll
        for (int r = 0; r < 4; ++r) {
            float val = acc[tt][r] + bias;
            if (o == 0) val *= QSCALE;
            tr[w][g * 4 + r][m] = f2bf(val);   // tr[q-or-kv row][d col]
        }
        if (o < 2) {
            if (g < 2) {
                short8 v8;
                #pragma unroll
                for (int j = 0; j < 8; ++j) v8[j] = (short)tr[w][m][g * 8 + j];
                unsigned short* dst = (o == 0) ? Qf : Kf;
                int c = t >> 1;
                *(short8*)&dst[(size_t)(blockIdx.x * 2 + c) * 512
                               + (((t & 1) * 2 + g) * 16 + m) * 8] = v8;
            }
        } else {
            if (g < 2) {
                short8 v8;
                #pragma unroll
                for (int j = 0; j < 8; ++j) v8[j] = (short)tr[w][g * 8 + j][m];
                *(short8*)&Vf[((size_t)(b2 * 128 + s) * 4 + t) * 512
                              + ((half * 2 + g) * 16 + m) * 8] = v8;
            }
        }
    }
}

// ---------------------------------------------------------------------------
// Kernel 2 (v5): causal flash attention; ALL operand loads are contiguous
// fragment-order 1KB/wave reads (Qf/Kf/Vf). Structure unchanged otherwise:
// 512 blocks x 512 thr, 32 q-rows/block, 8-way KV split, defer-max,
// free row-sum via ones-column MFMA, LDS combine.
// ---------------------------------------------------------------------------
__global__ void __launch_bounds__(512, 4) attn_kernel(
        const unsigned short* __restrict__ Qf,
        const unsigned short* __restrict__ Kf,
        const unsigned short* __restrict__ Vf,
        float* __restrict__ out) {
    __shared__ __align__(16) unsigned short P_lds[8][32][36];
    __shared__ __align__(16) unsigned short pacc[8][16][68];
    __shared__ float pm[8][16];
    __shared__ float pl[8][16];

    int j = blockIdx.x;
    int b = (j & 7) >> 1;
    int pair = 127 - ((j >> 3) * 2 + (j & 1));
    int q0 = pair * 32;
    int nsteps = pair + 1;
    int tid = threadIdx.x;
    int w = tid >> 6;
    int lane = tid & 63;
    int m = lane & 15, g = lane >> 4;

    // Q frags: contiguous 4KB for the two row-tiles
    const unsigned short* Qbase = Qf + (size_t)(b * 256 + pair * 2) * 1024 + lane * 8;
    short8 qf[2][2];
    qf[0][0] = *(const short8*)(Qbase);
    qf[0][1] = *(const short8*)(Qbase + 512);
    qf[1][0] = *(const short8*)(Qbase + 1024);
    qf[1][1] = *(const short8*)(Qbase + 1536);

    short8 onesB = (short8){0,0,0,0,0,0,0,0};
    if (m == 0) {
        #pragma unroll
        for (int jj = 0; jj < 8; ++jj) onesB[jj] = (short)0x3F80;
    }

    f32x4 acc[2][5];
    #pragma unroll
    for (int rt = 0; rt < 2; ++rt)
        #pragma unroll
        for (int t = 0; t < 5; ++t) acc[rt][t] = (f32x4){0.f, 0.f, 0.f, 0.f};
    float mrun[2][4];
    #pragma unroll
    for (int rt = 0; rt < 2; ++rt)
        #pragma unroll
        for (int r = 0; r < 4; ++r) mrun[rt][r] = -INFINITY;

    const unsigned short* Kbase = Kf + (size_t)(b * 256) * 1024 + lane * 8;
    const unsigned short* Vbase = Vf + (size_t)(b * 128) * 2048 + lane * 8;

    for (int s = w; s < nsteps; s += 8) {
        int kv0 = s * 32;
        // K step: 4 frags from one contiguous 4KB block
        short8 kf[4];
        kf[0] = *(const short8*)(Kbase + (size_t)s * 2048);
        kf[1] = *(const short8*)(Kbase + (size_t)s * 2048 + 512);
        kf[2] = *(const short8*)(Kbase + (size_t)s * 2048 + 1024);
        kf[3] = *(const short8*)(Kbase + (size_t)s * 2048 + 1536);
        // V step: 4 frags from one contiguous 4KB block
        short8 vcur[4];
        #pragma unroll
        for (int t = 0; t < 4; ++t)
            vcur[t] = *(const short8*)(Vbase + (size_t)s * 2048 + t * 512);
        bool last = (s == nsteps - 1);

        #pragma unroll
        for (int rt = 0; rt < 2; ++rt) {
            f32x4 sc[2];
            sc[0] = (f32x4){0.f, 0.f, 0.f, 0.f};
            sc[1] = (f32x4){0.f, 0.f, 0.f, 0.f};
            // note: kf[tt*2+c] with tt = kv half-tile, c = d chunk
            sc[0] = __builtin_amdgcn_mfma_f32_16x16x32_bf16(qf[rt][0], kf[0], sc[0], 0, 0, 0);
            sc[0] = __builtin_amdgcn_mfma_f32_16x16x32_bf16(qf[rt][1], kf[1], sc[0], 0, 0, 0);
            sc[1] = __builtin_amdgcn_mfma_f32_16x16x32_bf16(qf[rt][0], kf[2], sc[1], 0, 0, 0);
            sc[1] = __builtin_amdgcn_mfma_f32_16x16x32_bf16(qf[rt][1], kf[3], sc[1], 0, 0, 0);

            if (last) {
                #pragma unroll
                for (int tt = 0; tt < 2; ++tt)
                    #pragma unroll
                    for (int r = 0; r < 4; ++r)
                        if (kv0 + tt * 16 + m > q0 + rt * 16 + g * 4 + r) sc[tt][r] = -INFINITY;
            }

            bool need = false;
            #pragma unroll
            for (int r = 0; r < 4; ++r) {
                float th = mrun[rt][r] + 8.0f;
                need = need | (sc[0][r] > th) | (sc[1][r] > th);
            }
            if (__any(need)) {
                float rmax[4];
                #pragma unroll
                for (int r = 0; r < 4; ++r) rmax[r] = fmaxf(sc[0][r], sc[1][r]);
                #pragma unroll
                for (int msk = 1; msk <= 8; msk <<= 1)
                    #pragma unroll
                    for (int r = 0; r < 4; ++r)
                        rmax[r] = fmaxf(rmax[r], __shfl_xor(rmax[r], msk));
                #pragma unroll
                for (int r = 0; r < 4; ++r) {
                    float mnew = fmaxf(mrun[rt][r], rmax[r]);
                    float alpha = __builtin_amdgcn_exp2f(mrun[rt][r] - mnew);
                    mrun[rt][r] = mnew;
                    #pragma unroll
                    for (int t = 0; t < 5; ++t) acc[rt][t][r] *= alpha;
                }
            }

            #pragma unroll
            for (int tt = 0; tt < 2; ++tt)
                #pragma unroll
                for (int r = 0; r < 4; ++r)
                    P_lds[w][rt * 16 + g * 4 + r][tt * 16 + m] =
                        f2bf(__builtin_amdgcn_exp2f(sc[tt][r] - mrun[rt][r]));
            short8 pa = *(const short8*)&P_lds[w][rt * 16 + m][g * 8];

            #pragma unroll
            for (int t = 0; t < 4; ++t)
                acc[rt][t] = __builtin_amdgcn_mfma_f32_16x16x32_bf16(pa, vcur[t], acc[rt][t], 0, 0, 0);
            acc[rt][4] = __builtin_amdgcn_mfma_f32_16x16x32_bf16(pa, onesB, acc[rt][4], 0, 0, 0);
        }
    }

    #pragma unroll
    for (int rt = 0; rt < 2; ++rt) {
        if (m == 0) {
            #pragma unroll
            for (int r = 0; r < 4; ++r) {
                pm[w][g * 4 + r] = mrun[rt][r];
                pl[w][g * 4 + r] = acc[rt][4][r];
            }
        }
        #pragma unroll
        for (int t = 0; t < 4; ++t)
            #pragma unroll
            for (int r = 0; r < 4; ++r)
                pacc[w][g * 4 + r][t * 16 + m] = f2bf(acc[rt][t][r]);
        __syncthreads();

        if (tid < 256) {
            int row = tid >> 4;
            int c4 = (tid & 15) * 4;
            float mmax = pm[0][row];
            #pragma unroll
            for (int w2 = 1; w2 < 8; ++w2) mmax = fmaxf(mmax, pm[w2][row]);
            float lt = 0.f;
            float o0 = 0.f, o1 = 0.f, o2 = 0.f, o3 = 0.f;
            #pragma unroll
            for (int w2 = 0; w2 < 8; ++w2) {
                float sc2 = __builtin_amdgcn_exp2f(pm[w2][row] - mmax);
                lt += pl[w2][row] * sc2;
                short4v pa4 = *(const short4v*)&pacc[w2][row][c4];
                o0 += bf2f((unsigned short)pa4[0]) * sc2;
                o1 += bf2f((unsigned short)pa4[1]) * sc2;
                o2 += bf2f((unsigned short)pa4[2]) * sc2;
                o3 += bf2f((unsigned short)pa4[3]) * sc2;
            }
            float invl = 1.0f / lt;
            float4 res = make_float4(o0 * invl, o1 * invl, o2 * invl, o3 * invl);
            *(float4*)&out[(size_t)(b * SEQ + q0 + rt * 16 + row) * DOUT + c4] = res;
        }
        __syncthreads();
    }
}

// ---------------------------------------------------------------------------
extern "C" void kernel_launch(void* const* d_in, const int* in_sizes, int n_in,
                              void* d_out, int out_size, void* d_ws, size_t ws_size,
                              hipStream_t stream) {
    const float* x  = (const float*)d_in[0];
    const float* wq = (const float*)d_in[1];
    const float* bq = (const float*)d_in[2];
    const float* wk = (const float*)d_in[3];
    const float* bk = (const float*)d_in[4];
    const float* wv = (const float*)d_in[5];
    const float* bv = (const float*)d_in[6];
    float* out = (float*)d_out;

    char* ws = (char*)d_ws;
    unsigned short* wF = (unsigned short*)ws;                       // 294912 B
    unsigned short* Qf = (unsigned short*)(ws + 294912);            // 2 MB
    unsigned short* Kf = (unsigned short*)(ws + 294912 + 2097152);  // 2 MB
    unsigned short* Vf = (unsigned short*)(ws + 294912 + 4194304);  // 2 MB

    wprep_kernel<<<36, 256, 0, stream>>>(wq, wk, wv, wF);
    proj_kernel<<<1024, 256, 0, stream>>>(x, bq, bk, bv, wF, Qf, Kf, Vf);
    attn_kernel<<<512, 512, 0, stream>>>(Qf, Kf, Vf, out);
}